// Round 6
// baseline (425.068 us; speedup 1.0000x reference)
//
#include <hip/hip_runtime.h>
#include <stdint.h>

typedef unsigned short u16;
typedef __attribute__((ext_vector_type(8))) short    bf16x8;   // 8 bf16 in 4 VGPRs
typedef __attribute__((ext_vector_type(4))) float    f32x4;

// ---------- helpers ----------
__device__ __forceinline__ u16 f2bf(float f) {           // fp32 -> bf16, round-nearest-even
    unsigned u = __float_as_uint(f);
    u = (u + 0x7fffu + ((u >> 16) & 1u)) >> 16;
    return (u16)u;
}

// ---------- fp32 -> bf16 cast (vectorized) ----------
__global__ __launch_bounds__(256) void cast_bf16_kernel(const float* __restrict__ in,
                                                        u16* __restrict__ out, int n4) {
    int i = blockIdx.x * 256 + threadIdx.x;
    if (i < n4) {
        float4 f = ((const float4*)in)[i];
        ushort4 o;
        o.x = f2bf(f.x); o.y = f2bf(f.y); o.z = f2bf(f.z); o.w = f2bf(f.w);
        ((ushort4*)out)[i] = o;
    }
}

// cast the three weight matrices into one concatenated [2304][768] bf16 buffer
__global__ __launch_bounds__(256) void cast3_bf16_kernel(const float* __restrict__ w0,
                                                         const float* __restrict__ w1,
                                                         const float* __restrict__ w2,
                                                         u16* __restrict__ out) {
    const float* src = (blockIdx.y == 0) ? w0 : (blockIdx.y == 1) ? w1 : w2;
    int i = blockIdx.x * 256 + threadIdx.x;          // 576*256 = 147456 = 768*768/4
    float4 f = ((const float4*)src)[i];
    ushort4 o;
    o.x = f2bf(f.x); o.y = f2bf(f.y); o.z = f2bf(f.z); o.w = f2bf(f.w);
    ((ushort4*)out)[(size_t)blockIdx.y * 147456 + i] = o;
}

// ---------- bf16 32x32-tiled transpose: Vt[b][e][s] = V[b][s][e] (ld_in=2304) ----------
// also zeroes the rowsum buffer (it aliases the dead weight buffer; runs after proj GEMM)
__global__ __launch_bounds__(256) void transpose_bf16_kernel(const u16* __restrict__ V,
                                                             u16* __restrict__ Vt,
                                                             float* __restrict__ rsum) {
    __shared__ u16 tile[32][33];
    const int t = threadIdx.x;
    if (blockIdx.x == 0 && blockIdx.z == 0) {
        int idx = blockIdx.y * 256 + t;
        if (idx < 16384) rsum[idx] = 0.f;
    }
    const size_t z = blockIdx.z;
    const u16* Vb  = V  + z * (size_t)4096 * 2304;
    u16*       Vtb = Vt + z * (size_t)768 * 4096;
    const int c0 = blockIdx.x * 32;           // D (col) tile
    const int r0 = blockIdx.y * 32;           // S (row) tile
    const int lr = t >> 3;                    // 0..31
    const int lc = (t & 7) * 4;               // 0..28
    ushort4 in = *(const ushort4*)&Vb[(size_t)(r0 + lr) * 2304 + c0 + lc];
    tile[lr][lc + 0] = in.x; tile[lr][lc + 1] = in.y;
    tile[lr][lc + 2] = in.z; tile[lr][lc + 3] = in.w;
    __syncthreads();
    ushort4 o;
    o.x = tile[lc + 0][lr]; o.y = tile[lc + 1][lr];
    o.z = tile[lc + 2][lr]; o.w = tile[lc + 3][lr];
    *(ushort4*)&Vtb[(size_t)(c0 + lr) * 4096 + r0 + lc] = o;
}

// ---------- GEMM, BK=64, reg-staged prefetch: C[m][n] = sum_k A[m][k]*B[n][k] ----------
// Block tile 128 x (32*WN); 4 waves in 2x2; wave tile 64 x (16*WN) via 4xWN MFMA 16x16x32.
//   WN=8: fat tile (64 MFMA / 36 LDS-ops per wave-iter) -- for QK & proj.
//   WN=4: original 128x128 (for PV, where N=768 limits the grid).
// Pipeline: tile k+1 global->VGPR during tile k's MFMA phase, ds_write after barrier.
// LDS XOR swizzle: chunk (r,c) holds global chunk (r, c^(r&7)) -- conflict-free (R4: 0).
// EPI: 0 = +bias[col] (b0/b1/b2 per 768-col segment), bf16 out            (QKV projection)
//      1 = exp2(acc*s2), bf16 out, atomicAdd row sums into rs             (QK^T -> E)
//      2 = acc * (1/rs[row]), fp32 out                                    (E*Vt -> O)
// Grid 1D = NGRID, two-level XCD swizzle: lin%8 = XCD; bx-group of GRP innermost,
// strips middle, groups outer -> concurrent working set sized to the 4 MB per-XCD L2.
template <int EPI, int WN, int NBX, int GRP, int NGRID, int NBY, int MINW>
__global__ __launch_bounds__(256, MINW) void gemm_bt_kernel(
        const u16* __restrict__ A, const u16* __restrict__ B, void* __restrict__ Cv,
        const float* __restrict__ b0, const float* __restrict__ b1, const float* __restrict__ b2,
        float* __restrict__ rs, float s2, int K,
        int lda, int ldb, int ldc, long batchA, long batchB, long batchC) {
    __shared__ __align__(16) u16 As[128 * 64];
    __shared__ __align__(16) u16 Bs[32 * WN * 64];

    constexpr int SPX = NGRID / (8 * NBX);        // strips per XCD
    const int lin = blockIdx.x;
    const int c = lin & 7, p = lin >> 3;
    const int bxi = p % GRP;
    const int rest = p / GRP;
    const int s = rest % SPX;
    const int g = rest / SPX;
    const int bx = g * GRP + bxi;
    const int strip = c * SPX + s;
    const int by = strip % NBY;
    const int bz = strip / NBY;

    const int t = threadIdx.x;
    const long z = bz;
    const u16* Ab = A + z * batchA + (long)by * 128 * lda;
    const u16* Bb = B + z * batchB + (long)bx * (32 * WN) * ldb;

    const int lane = t & 63;
    const int wave = t >> 6;
    const int wm = wave >> 1, wn = wave & 1;      // 2x2 wave grid
    const int quad = lane >> 4;
    const int frow = lane & 15;
    const int cc0 = quad ^ (frow & 7);            // swizzled chunk col for k-chunk 0

    f32x4 acc[4][WN];
#pragma unroll
    for (int i = 0; i < 4; i++)
#pragma unroll
        for (int j = 0; j < WN; j++)
#pragma unroll
            for (int e = 0; e < 4; e++) acc[i][j][e] = 0.f;

    // staging map: dest chunk d=(r,c8) sources global chunk (r, c8^(r&7)).
    // A: 1024 chunks (j<4); B: 256*WN chunks (j<WN). Same formula, shared arrays.
    int srow[WN], scol[WN];
#pragma unroll
    for (int j = 0; j < WN; j++) {
        const int d = t + j * 256;
        srow[j] = d >> 3;
        scol[j] = ((d & 7) ^ (srow[j] & 7)) * 8;
    }

    // register-staged prefetch buffers
    bf16x8 ra[4], rb[WN];
#pragma unroll
    for (int j = 0; j < 4; j++)
        ra[j] = *(const bf16x8*)(Ab + (long)srow[j] * lda + scol[j]);
#pragma unroll
    for (int j = 0; j < WN; j++)
        rb[j] = *(const bf16x8*)(Bb + (long)srow[j] * ldb + scol[j]);

    for (int kt = 0; kt < K; kt += 64) {
        // commit prefetched tile to LDS (loads were issued one compute-phase ago)
#pragma unroll
        for (int j = 0; j < 4; j++)
            *(bf16x8*)&As[(t + j * 256) * 8] = ra[j];
#pragma unroll
        for (int j = 0; j < WN; j++)
            *(bf16x8*)&Bs[(t + j * 256) * 8] = rb[j];
        __syncthreads();

        // issue next tile's global loads; they fly during the MFMA phase below
        if (kt + 64 < K) {
            const int kn = kt + 64;
#pragma unroll
            for (int j = 0; j < 4; j++)
                ra[j] = *(const bf16x8*)(Ab + (long)srow[j] * lda + kn + scol[j]);
#pragma unroll
            for (int j = 0; j < WN; j++)
                rb[j] = *(const bf16x8*)(Bb + (long)srow[j] * ldb + kn + scol[j]);
        }

#pragma unroll
        for (int kk = 0; kk < 2; kk++) {
            const int cc = (cc0 ^ (kk * 4)) * 8;
            bf16x8 bfr[WN];
#pragma unroll
            for (int j = 0; j < WN; j++)
                bfr[j] = *(const bf16x8*)&Bs[(wn * WN * 16 + j * 16 + frow) * 64 + cc];
#pragma unroll
            for (int i = 0; i < 4; i++) {
                bf16x8 af = *(const bf16x8*)&As[(wm * 64 + i * 16 + frow) * 64 + cc];
#pragma unroll
                for (int j = 0; j < WN; j++)
                    acc[i][j] = __builtin_amdgcn_mfma_f32_16x16x32_bf16(af, bfr[j], acc[i][j], 0, 0, 0);
            }
        }
        __syncthreads();   // LDS readers done before next iter's ds_write
    }

    // epilogue: C/D layout col = lane&15 (n), row = quad*4 + reg (m)  [m89-verified]
    const int m_base = by * 128 + wm * 64;
    const int n_base = bx * (32 * WN) + wn * (16 * WN);

    if (EPI == 0) {
        const int seg = n_base / 768;             // uniform per wave; tile fits one segment
        const float* bp = (seg == 0) ? b0 : (seg == 1) ? b1 : b2;
        u16* C = (u16*)Cv + z * batchC;
#pragma unroll
        for (int j = 0; j < WN; j++) {
            const int col = n_base + j * 16 + frow;
            const float bb = bp[col - seg * 768];
#pragma unroll
            for (int i = 0; i < 4; i++) {
                const int row0 = m_base + i * 16 + quad * 4;
#pragma unroll
                for (int r = 0; r < 4; r++)
                    C[(long)(row0 + r) * ldc + col] = f2bf(acc[i][j][r] + bb);
            }
        }
    } else if (EPI == 1) {
        u16* C = (u16*)Cv + z * batchC;
        float rowpart[4][4];
#pragma unroll
        for (int i = 0; i < 4; i++)
#pragma unroll
            for (int r = 0; r < 4; r++) rowpart[i][r] = 0.f;
#pragma unroll
        for (int i = 0; i < 4; i++) {
            const int row0 = m_base + i * 16 + quad * 4;
#pragma unroll
            for (int j = 0; j < WN; j++) {
                const int col = n_base + j * 16 + frow;
#pragma unroll
                for (int r = 0; r < 4; r++) {
                    float e = exp2f(acc[i][j][r] * s2);
                    C[(long)(row0 + r) * ldc + col] = f2bf(e);
                    rowpart[i][r] += e;
                }
            }
        }
        // reduce each row's partial over the 16 frow lanes, then one atomic per row
#pragma unroll
        for (int i = 0; i < 4; i++)
#pragma unroll
            for (int r = 0; r < 4; r++) {
                float v = rowpart[i][r];
                v += __shfl_xor(v, 1); v += __shfl_xor(v, 2);
                v += __shfl_xor(v, 4); v += __shfl_xor(v, 8);
                if (frow == 0)
                    atomicAdd(&rs[z * 4096 + m_base + i * 16 + quad * 4 + r], v);
            }
    } else {
        float* C = (float*)Cv + z * batchC;
#pragma unroll
        for (int i = 0; i < 4; i++) {
            const int row0 = m_base + i * 16 + quad * 4;
            float inv[4];
#pragma unroll
            for (int r = 0; r < 4; r++) inv[r] = 1.0f / rs[z * 4096 + row0 + r];
#pragma unroll
            for (int j = 0; j < WN; j++) {
                const int col = n_base + j * 16 + frow;
#pragma unroll
                for (int r = 0; r < 4; r++)
                    C[(long)(row0 + r) * ldc + col] = acc[i][j][r] * inv[r];
            }
        }
    }
}

extern "C" void kernel_launch(void* const* d_in, const int* in_sizes, int n_in,
                              void* d_out, int out_size, void* d_ws, size_t ws_size,
                              hipStream_t stream) {
    const float* x  = (const float*)d_in[0];
    const float* Wq = (const float*)d_in[1];
    const float* bq = (const float*)d_in[2];
    const float* Wk = (const float*)d_in[3];
    const float* bk = (const float*)d_in[4];
    const float* Wv = (const float*)d_in[5];
    const float* bv = (const float*)d_in[6];
    float* out = (float*)d_out;

    // B=4, S=4096, D=768; 16384 tokens. Workspace layout (total 238,419,968 B):
    //  @0          : xb bf16 [16384][768]      (25,165,824)  -- dead after proj; Vt reuses it
    //  @25,165,824 : QKV bf16 [16384][2304]    (75,497,472)
    //  @100,663,296: E bf16 [4][4096][4096]    (134,217,728)
    //  @234,881,024: Wqkv bf16 [2304][768]     (3,538,944)   -- dead after proj;
    //                 rowsum fp32[16384] (65,536) aliases its head, zeroed in transpose
    uint8_t* ws = (uint8_t*)d_ws;
    u16*   xb   = (u16*)(ws + 0);
    u16*   Vt   = (u16*)(ws + 0);
    u16*   QKV  = (u16*)(ws + 25165824);
    u16*   E    = (u16*)(ws + 100663296);
    u16*   Wqkv = (u16*)(ws + 234881024);
    float* rsum = (float*)(ws + 234881024);

    // 1) casts
    cast_bf16_kernel<<<12288, 256, 0, stream>>>(x, xb, 3145728);
    cast3_bf16_kernel<<<dim3(576, 3), 256, 0, stream>>>(Wq, Wk, Wv, Wqkv);

    // 2) fused QKV projection: [16384,768] x [2304,768]^T + bias -> QKV bf16 (ldc 2304)
    //    fat tile 128x256: NBX=9, GRP=9 (full 3.5 MB W-panel L2-locked per XCD)
    gemm_bt_kernel<0, 8, 9, 9, 1152, 128, 2><<<1152, 256, 0, stream>>>(
        xb, Wqkv, QKV, bq, bk, bv, nullptr, 0.f, 768, 768, 768, 2304, 0, 0, 0);

    // 3) V transpose per batch (V = QKV cols [1536,2304), ld 2304) -> Vt[e][s]; zero rowsum
    transpose_bf16_kernel<<<dim3(24, 128, 4), 256, 0, stream>>>(QKV + 1536, Vt, rsum);

    // 4) E = exp(scale * Q K^T) (per batch, 4096x4096, K=768) + rowsum atomics
    //    s2 = (1/sqrt(768)) * log2(e); fat tile 128x256: NBX=16, GRP=4
    gemm_bt_kernel<1, 8, 16, 4, 2048, 32, 2><<<2048, 256, 0, stream>>>(
        QKV, QKV + 768, E, nullptr, nullptr, nullptr, rsum, 0.05205954822032348f,
        768, 2304, 2304, 4096, (long)4096 * 2304, (long)4096 * 2304, (long)4096 * 4096);

    // 5) O = (E Vt^T) / rowsum -> fp32 out (per batch, M=4096, N=768, K=4096)
    //    keeps WN=4 (128x128) config: N=768 -> only 6 bx, fat tile would starve the grid
    gemm_bt_kernel<2, 4, 6, 6, 768, 32, 3><<<768, 256, 0, stream>>>(
        E, Vt, out, nullptr, nullptr, nullptr, rsum, 0.f,
        4096, 4096, 4096, 768, (long)4096 * 4096, (long)768 * 4096, (long)4096 * 768);
}

// Round 7
// 403.961 us; speedup vs baseline: 1.0523x; 1.0523x over previous
//
#include <hip/hip_runtime.h>
#include <stdint.h>

typedef unsigned short u16;
typedef __attribute__((ext_vector_type(8))) short    bf16x8;   // 8 bf16 in 4 VGPRs
typedef __attribute__((ext_vector_type(4))) float    f32x4;

// ---------- helpers ----------
__device__ __forceinline__ u16 f2bf(float f) {           // fp32 -> bf16, round-nearest-even
    unsigned u = __float_as_uint(f);
    u = (u + 0x7fffu + ((u >> 16) & 1u)) >> 16;
    return (u16)u;
}

// ---------- fp32 -> bf16 cast (vectorized) ----------
__global__ __launch_bounds__(256) void cast_bf16_kernel(const float* __restrict__ in,
                                                        u16* __restrict__ out, int n4) {
    int i = blockIdx.x * 256 + threadIdx.x;
    if (i < n4) {
        float4 f = ((const float4*)in)[i];
        ushort4 o;
        o.x = f2bf(f.x); o.y = f2bf(f.y); o.z = f2bf(f.z); o.w = f2bf(f.w);
        ((ushort4*)out)[i] = o;
    }
}

// cast the three weight matrices into one concatenated [2304][768] bf16 buffer
__global__ __launch_bounds__(256) void cast3_bf16_kernel(const float* __restrict__ w0,
                                                         const float* __restrict__ w1,
                                                         const float* __restrict__ w2,
                                                         u16* __restrict__ out) {
    const float* src = (blockIdx.y == 0) ? w0 : (blockIdx.y == 1) ? w1 : w2;
    int i = blockIdx.x * 256 + threadIdx.x;          // 576*256 = 147456 = 768*768/4
    float4 f = ((const float4*)src)[i];
    ushort4 o;
    o.x = f2bf(f.x); o.y = f2bf(f.y); o.z = f2bf(f.z); o.w = f2bf(f.w);
    ((ushort4*)out)[(size_t)blockIdx.y * 147456 + i] = o;
}

// ---------- bf16 32x32-tiled transpose: Vt[b][e][s] = V[b][s][e] (ld_in=2304) ----------
// also zeroes the rowsum buffer (it aliases the dead weight buffer; runs after proj GEMM)
__global__ __launch_bounds__(256) void transpose_bf16_kernel(const u16* __restrict__ V,
                                                             u16* __restrict__ Vt,
                                                             float* __restrict__ rsum) {
    __shared__ u16 tile[32][33];
    const int t = threadIdx.x;
    if (blockIdx.x == 0 && blockIdx.z == 0) {
        int idx = blockIdx.y * 256 + t;
        if (idx < 16384) rsum[idx] = 0.f;
    }
    const size_t z = blockIdx.z;
    const u16* Vb  = V  + z * (size_t)4096 * 2304;
    u16*       Vtb = Vt + z * (size_t)768 * 4096;
    const int c0 = blockIdx.x * 32;           // D (col) tile
    const int r0 = blockIdx.y * 32;           // S (row) tile
    const int lr = t >> 3;                    // 0..31
    const int lc = (t & 7) * 4;               // 0..28
    ushort4 in = *(const ushort4*)&Vb[(size_t)(r0 + lr) * 2304 + c0 + lc];
    tile[lr][lc + 0] = in.x; tile[lr][lc + 1] = in.y;
    tile[lr][lc + 2] = in.z; tile[lr][lc + 3] = in.w;
    __syncthreads();
    ushort4 o;
    o.x = tile[lc + 0][lr]; o.y = tile[lc + 1][lr];
    o.z = tile[lc + 2][lr]; o.w = tile[lc + 3][lr];
    *(ushort4*)&Vtb[(size_t)(c0 + lr) * 4096 + r0 + lc] = o;
}

// ---------- GEMM, BK=64, reg-staged prefetch: C[m][n] = sum_k A[m][k]*B[n][k] ----------
// Block tile 128 x (32*WN); 4 waves in 2x2; wave tile 64 x (16*WN) via 4xWN MFMA 16x16x32.
//   WN=8 (fat): only for long-K + large-grid cases (QK: 24 iters, 2048 blocks).
//   WN=4 (thin): proj (short K=768 -> tail/prologue dominate at 2 blk/CU; R6 measured
//                regression with fat) and PV (N=768 caps the grid).
// Pipeline: tile k+1 global->VGPR during tile k's MFMA phase, ds_write after barrier.
// LDS XOR swizzle: chunk (r,c) holds global chunk (r, c^(r&7)) -- conflict-free (R4: 0).
// EPI: 0 = +bias[col] (b0/b1/b2 per 768-col segment), bf16 out            (QKV projection)
//      1 = exp2(acc*s2), bf16 out, atomicAdd row sums into rs             (QK^T -> E)
//      2 = acc * (1/rs[row]), fp32 out                                    (E*Vt -> O)
// Grid 1D = NGRID, two-level XCD swizzle: lin%8 = XCD; bx-group of GRP innermost,
// strips middle, groups outer -> concurrent working set sized to the 4 MB per-XCD L2.
template <int EPI, int WN, int NBX, int GRP, int NGRID, int NBY, int MINW>
__global__ __launch_bounds__(256, MINW) void gemm_bt_kernel(
        const u16* __restrict__ A, const u16* __restrict__ B, void* __restrict__ Cv,
        const float* __restrict__ b0, const float* __restrict__ b1, const float* __restrict__ b2,
        float* __restrict__ rs, float s2, int K,
        int lda, int ldb, int ldc, long batchA, long batchB, long batchC) {
    __shared__ __align__(16) u16 As[128 * 64];
    __shared__ __align__(16) u16 Bs[32 * WN * 64];

    constexpr int SPX = NGRID / (8 * NBX);        // strips per XCD
    const int lin = blockIdx.x;
    const int c = lin & 7, p = lin >> 3;
    const int bxi = p % GRP;
    const int rest = p / GRP;
    const int s = rest % SPX;
    const int g = rest / SPX;
    const int bx = g * GRP + bxi;
    const int strip = c * SPX + s;
    const int by = strip % NBY;
    const int bz = strip / NBY;

    const int t = threadIdx.x;
    const long z = bz;
    const u16* Ab = A + z * batchA + (long)by * 128 * lda;
    const u16* Bb = B + z * batchB + (long)bx * (32 * WN) * ldb;

    const int lane = t & 63;
    const int wave = t >> 6;
    const int wm = wave >> 1, wn = wave & 1;      // 2x2 wave grid
    const int quad = lane >> 4;
    const int frow = lane & 15;
    const int cc0 = quad ^ (frow & 7);            // swizzled chunk col for k-chunk 0

    f32x4 acc[4][WN];
#pragma unroll
    for (int i = 0; i < 4; i++)
#pragma unroll
        for (int j = 0; j < WN; j++)
#pragma unroll
            for (int e = 0; e < 4; e++) acc[i][j][e] = 0.f;

    // staging map: dest chunk d=(r,c8) sources global chunk (r, c8^(r&7)).
    // A: 1024 chunks (j<4); B: 256*WN chunks (j<WN). Same formula, shared arrays.
    int srow[WN], scol[WN];
#pragma unroll
    for (int j = 0; j < WN; j++) {
        const int d = t + j * 256;
        srow[j] = d >> 3;
        scol[j] = ((d & 7) ^ (srow[j] & 7)) * 8;
    }

    // register-staged prefetch buffers
    bf16x8 ra[4], rb[WN];
#pragma unroll
    for (int j = 0; j < 4; j++)
        ra[j] = *(const bf16x8*)(Ab + (long)srow[j] * lda + scol[j]);
#pragma unroll
    for (int j = 0; j < WN; j++)
        rb[j] = *(const bf16x8*)(Bb + (long)srow[j] * ldb + scol[j]);

    for (int kt = 0; kt < K; kt += 64) {
        // commit prefetched tile to LDS (loads were issued one compute-phase ago)
#pragma unroll
        for (int j = 0; j < 4; j++)
            *(bf16x8*)&As[(t + j * 256) * 8] = ra[j];
#pragma unroll
        for (int j = 0; j < WN; j++)
            *(bf16x8*)&Bs[(t + j * 256) * 8] = rb[j];
        __syncthreads();

        // issue next tile's global loads; they fly during the MFMA phase below
        if (kt + 64 < K) {
            const int kn = kt + 64;
#pragma unroll
            for (int j = 0; j < 4; j++)
                ra[j] = *(const bf16x8*)(Ab + (long)srow[j] * lda + kn + scol[j]);
#pragma unroll
            for (int j = 0; j < WN; j++)
                rb[j] = *(const bf16x8*)(Bb + (long)srow[j] * ldb + kn + scol[j]);
        }

#pragma unroll
        for (int kk = 0; kk < 2; kk++) {
            const int cc = (cc0 ^ (kk * 4)) * 8;
            bf16x8 bfr[WN];
#pragma unroll
            for (int j = 0; j < WN; j++)
                bfr[j] = *(const bf16x8*)&Bs[(wn * WN * 16 + j * 16 + frow) * 64 + cc];
#pragma unroll
            for (int i = 0; i < 4; i++) {
                bf16x8 af = *(const bf16x8*)&As[(wm * 64 + i * 16 + frow) * 64 + cc];
#pragma unroll
                for (int j = 0; j < WN; j++)
                    acc[i][j] = __builtin_amdgcn_mfma_f32_16x16x32_bf16(af, bfr[j], acc[i][j], 0, 0, 0);
            }
        }
        __syncthreads();   // LDS readers done before next iter's ds_write
    }

    // epilogue: C/D layout col = lane&15 (n), row = quad*4 + reg (m)  [m89-verified]
    const int m_base = by * 128 + wm * 64;
    const int n_base = bx * (32 * WN) + wn * (16 * WN);

    if (EPI == 0) {
        const int seg = n_base / 768;             // uniform per wave; tile fits one segment
        const float* bp = (seg == 0) ? b0 : (seg == 1) ? b1 : b2;
        u16* C = (u16*)Cv + z * batchC;
#pragma unroll
        for (int j = 0; j < WN; j++) {
            const int col = n_base + j * 16 + frow;
            const float bb = bp[col - seg * 768];
#pragma unroll
            for (int i = 0; i < 4; i++) {
                const int row0 = m_base + i * 16 + quad * 4;
#pragma unroll
                for (int r = 0; r < 4; r++)
                    C[(long)(row0 + r) * ldc + col] = f2bf(acc[i][j][r] + bb);
            }
        }
    } else if (EPI == 1) {
        u16* C = (u16*)Cv + z * batchC;
        float rowpart[4][4];
#pragma unroll
        for (int i = 0; i < 4; i++)
#pragma unroll
            for (int r = 0; r < 4; r++) rowpart[i][r] = 0.f;
#pragma unroll
        for (int i = 0; i < 4; i++) {
            const int row0 = m_base + i * 16 + quad * 4;
#pragma unroll
            for (int j = 0; j < WN; j++) {
                const int col = n_base + j * 16 + frow;
#pragma unroll
                for (int r = 0; r < 4; r++) {
                    float e = exp2f(acc[i][j][r] * s2);
                    C[(long)(row0 + r) * ldc + col] = f2bf(e);
                    rowpart[i][r] += e;
                }
            }
        }
        // reduce each row's partial over the 16 frow lanes, then one atomic per row
#pragma unroll
        for (int i = 0; i < 4; i++)
#pragma unroll
            for (int r = 0; r < 4; r++) {
                float v = rowpart[i][r];
                v += __shfl_xor(v, 1); v += __shfl_xor(v, 2);
                v += __shfl_xor(v, 4); v += __shfl_xor(v, 8);
                if (frow == 0)
                    atomicAdd(&rs[z * 4096 + m_base + i * 16 + quad * 4 + r], v);
            }
    } else {
        float* C = (float*)Cv + z * batchC;
#pragma unroll
        for (int i = 0; i < 4; i++) {
            const int row0 = m_base + i * 16 + quad * 4;
            float inv[4];
#pragma unroll
            for (int r = 0; r < 4; r++) inv[r] = 1.0f / rs[z * 4096 + row0 + r];
#pragma unroll
            for (int j = 0; j < WN; j++) {
                const int col = n_base + j * 16 + frow;
#pragma unroll
                for (int r = 0; r < 4; r++)
                    C[(long)(row0 + r) * ldc + col] = acc[i][j][r] * inv[r];
            }
        }
    }
}

extern "C" void kernel_launch(void* const* d_in, const int* in_sizes, int n_in,
                              void* d_out, int out_size, void* d_ws, size_t ws_size,
                              hipStream_t stream) {
    const float* x  = (const float*)d_in[0];
    const float* Wq = (const float*)d_in[1];
    const float* bq = (const float*)d_in[2];
    const float* Wk = (const float*)d_in[3];
    const float* bk = (const float*)d_in[4];
    const float* Wv = (const float*)d_in[5];
    const float* bv = (const float*)d_in[6];
    float* out = (float*)d_out;

    // B=4, S=4096, D=768; 16384 tokens. Workspace layout (total 238,419,968 B):
    //  @0          : xb bf16 [16384][768]      (25,165,824)  -- dead after proj; Vt reuses it
    //  @25,165,824 : QKV bf16 [16384][2304]    (75,497,472)
    //  @100,663,296: E bf16 [4][4096][4096]    (134,217,728)
    //  @234,881,024: Wqkv bf16 [2304][768]     (3,538,944)   -- dead after proj;
    //                 rowsum fp32[16384] (65,536) aliases its head, zeroed in transpose
    uint8_t* ws = (uint8_t*)d_ws;
    u16*   xb   = (u16*)(ws + 0);
    u16*   Vt   = (u16*)(ws + 0);
    u16*   QKV  = (u16*)(ws + 25165824);
    u16*   E    = (u16*)(ws + 100663296);
    u16*   Wqkv = (u16*)(ws + 234881024);
    float* rsum = (float*)(ws + 234881024);

    // 1) casts
    cast_bf16_kernel<<<12288, 256, 0, stream>>>(x, xb, 3145728);
    cast3_bf16_kernel<<<dim3(576, 3), 256, 0, stream>>>(Wq, Wk, Wv, Wqkv);

    // 2) fused QKV projection: [16384,768] x [2304,768]^T + bias -> QKV bf16 (ldc 2304)
    //    THIN tile (R5-proven): short K=768 punishes fat tiles (R6: +28 us). GRP=6.
    gemm_bt_kernel<0, 4, 18, 6, 2304, 128, 3><<<2304, 256, 0, stream>>>(
        xb, Wqkv, QKV, bq, bk, bv, nullptr, 0.f, 768, 768, 768, 2304, 0, 0, 0);

    // 3) V transpose per batch (V = QKV cols [1536,2304), ld 2304) -> Vt[e][s]; zero rowsum
    transpose_bf16_kernel<<<dim3(24, 128, 4), 256, 0, stream>>>(QKV + 1536, Vt, rsum);

    // 4) E = exp(scale * Q K^T) (per batch, 4096x4096, K=768) + rowsum atomics
    //    s2 = (1/sqrt(768)) * log2(e); FAT tile 128x256 (R6-proven: 150->135 us)
    gemm_bt_kernel<1, 8, 16, 4, 2048, 32, 2><<<2048, 256, 0, stream>>>(
        QKV, QKV + 768, E, nullptr, nullptr, nullptr, rsum, 0.05205954822032348f,
        768, 2304, 2304, 4096, (long)4096 * 2304, (long)4096 * 2304, (long)4096 * 4096);

    // 5) O = (E Vt^T) / rowsum -> fp32 out (per batch, M=4096, N=768, K=4096)
    //    THIN tile: N=768 -> 6 bx, 768 blocks = exactly 3/CU resident, zero tail
    gemm_bt_kernel<2, 4, 6, 6, 768, 32, 3><<<768, 256, 0, stream>>>(
        E, Vt, out, nullptr, nullptr, nullptr, rsum, 0.f,
        4096, 4096, 4096, 768, (long)4096 * 4096, (long)768 * 4096, (long)4096 * 768);
}